// Round 7
// baseline (240.255 us; speedup 1.0000x reference)
//
#include <hip/hip_runtime.h>
#include <stdint.h>

typedef unsigned short u16;
typedef u16 u16x4 __attribute__((ext_vector_type(4)));
typedef u16 u16x8 __attribute__((ext_vector_type(8)));
typedef __bf16 bf16x8 __attribute__((ext_vector_type(8)));
typedef float f32x4 __attribute__((ext_vector_type(4)));

#define NSER 4096
#define KDIM 4096
#define NCOLS 288                 // 264 padded to 288
#define MATSZ (NCOLS * NSER)      // elements per transposed bf16 mat buffer
#define PE ((size_t)NCOLS * NSER) // fp32 partial slot elements (1,179,648)

__device__ __forceinline__ u16 f2bf(float f) {
  uint32_t u = __builtin_bit_cast(uint32_t, f);
  u += 0x7FFFu + ((u >> 16) & 1u);   // RNE; inputs are never NaN
  return (u16)(u >> 16);
}
__device__ __forceinline__ float bf2f(u16 h) {
  return __builtin_bit_cast(float, (uint32_t)h << 16);
}

// ---------------- build X^T [288][4096] bf16 ----------------
// Xt[f*4+b][n] = xs[b,n,f];  f<2 -> inputs[b][n*2+f], f>=2 -> state[b][n*64+(f-2)]
__global__ __launch_bounds__(256) void k_build_x(const float* __restrict__ inputs,
                                                 const float* __restrict__ state,
                                                 u16* __restrict__ xb) {
  __shared__ float tile[64][65];
  const int nt = blockIdx.x, b = blockIdx.y;
  const int n0 = nt * 64;
  const int t = threadIdx.x;
  {
    const int i = t >> 2;
    const int c0 = (t & 3) * 16;
    const float* sp = state + ((int64_t)b * NSER + (n0 + i)) * 64 + c0;
    #pragma unroll
    for (int q = 0; q < 4; ++q) {
      float4 v = *(const float4*)(sp + q * 4);
      tile[i][c0 + q * 4 + 0] = v.x;
      tile[i][c0 + q * 4 + 1] = v.y;
      tile[i][c0 + q * 4 + 2] = v.z;
      tile[i][c0 + q * 4 + 3] = v.w;
    }
  }
  __syncthreads();
  const int wv = t >> 6, lane = t & 63;
  #pragma unroll
  for (int it = 0; it < 16; ++it) {
    const int d = wv + 4 * it;  // 0..63
    xb[(size_t)((2 + d) * 4 + b) * NSER + n0 + lane] = f2bf(tile[lane][d]);
  }
  if (t < 128) {
    const int c = t >> 6, j = t & 63;
    xb[(size_t)(c * 4 + b) * NSER + n0 + j] =
        f2bf(inputs[(int64_t)b * (NSER * 2) + (int64_t)(n0 + j) * 2 + c]);
  }
  if (b == 0) {  // zero pad rows 264..287
    for (int idx = t; idx < 24 * 64; idx += 256)
      xb[(size_t)(264 + idx / 64) * NSER + n0 + (idx & 63)] = 0;
  }
}

// ---------------- LDS-free GEMM: P[z][j][i] = sum_k A[i][k] * B^T[j][k] ----------------
// Each wave: 32-row A strip (mf=2 16-row frags) x full N=288 (nf=18), acc 2x18 f32x4.
// MFMA fragments loaded DIRECTLY from global (A fp32 -> reg cvt; B bf16 b128).
// No LDS, no barriers. 2 waves/block. Fragment layout identical to the proven
// LDS kernel: A row=lane&15, k=(lane>>4)*8+e; C/D col(j)=lane&15, row(i)=(lane>>4)*4+r.
template <int KCC>
__global__ __launch_bounds__(128, 1) void k_gemm(const float* __restrict__ A0f,
                                                 const float* __restrict__ A1f,
                                                 const u16* __restrict__ Bm,
                                                 float* __restrict__ Pb) {
  int kc = blockIdx.z;
  const float* Af = A0f;
  if (kc >= KCC) { Af = A1f; kc -= KCC; }
  const int lane = threadIdx.x & 63;
  const int w = threadIdx.x >> 6;             // 0..1
  const int i0w = blockIdx.x * 64 + w * 32;   // this wave's 32-row strip
  const int KCH = KDIM / KCC;
  const int NK = KCH / 32;                    // ksteps of K=32
  const int k0 = kc * KCH;

  const int l15 = lane & 15;
  const int koff = (lane >> 4) * 8;           // k offset within the 32-slice

  const float* pA0 = Af + (size_t)(i0w + l15) * KDIM + k0 + koff;
  const float* pA1 = pA0 + (size_t)16 * KDIM;
  const char* bB = (const char*)Bm + ((size_t)l15 * KDIM + k0 + koff) * 2;

  f32x4 acc[2][18];
  #pragma unroll
  for (int s = 0; s < 2; ++s)
    #pragma unroll
    for (int nf = 0; nf < 18; ++nf) acc[s][nf] = (f32x4){0.f, 0.f, 0.f, 0.f};

  #pragma unroll 2
  for (int ks = 0; ks < NK; ++ks) {
    const int kb = ks * 32;
    // A loads (issued first)
    f32x4 a00 = *(const f32x4*)(pA0 + kb);
    f32x4 a01 = *(const f32x4*)(pA0 + kb + 4);
    f32x4 a10 = *(const f32x4*)(pA1 + kb);
    f32x4 a11 = *(const f32x4*)(pA1 + kb + 4);
    const char* bptr = bB + (size_t)kb * 2;
    // B groups of 6 (row stride 16*KDIM*2 = 131072 B per nf)
    bf16x8 bva[6], bvb[6];
    #pragma unroll
    for (int q = 0; q < 6; ++q)
      bva[q] = *(const bf16x8*)(bptr + (size_t)q * (16 * KDIM * 2));
    #pragma unroll
    for (int q = 0; q < 6; ++q)
      bvb[q] = *(const bf16x8*)(bptr + (size_t)(6 + q) * (16 * KDIM * 2));
    // cvt A -> bf16 frags
    u16x8 w0, w1;
    #pragma unroll
    for (int q = 0; q < 4; ++q) {
      w0[q] = f2bf(a00[q]); w0[4 + q] = f2bf(a01[q]);
      w1[q] = f2bf(a10[q]); w1[4 + q] = f2bf(a11[q]);
    }
    const bf16x8 af0 = __builtin_bit_cast(bf16x8, w0);
    const bf16x8 af1 = __builtin_bit_cast(bf16x8, w1);
    // group 0 MFMA
    #pragma unroll
    for (int q = 0; q < 6; ++q) {
      acc[0][q] = __builtin_amdgcn_mfma_f32_16x16x32_bf16(af0, bva[q], acc[0][q], 0, 0, 0);
      acc[1][q] = __builtin_amdgcn_mfma_f32_16x16x32_bf16(af1, bva[q], acc[1][q], 0, 0, 0);
    }
    // load group 2 while group 1 computes
    #pragma unroll
    for (int q = 0; q < 6; ++q)
      bva[q] = *(const bf16x8*)(bptr + (size_t)(12 + q) * (16 * KDIM * 2));
    #pragma unroll
    for (int q = 0; q < 6; ++q) {
      acc[0][6 + q] = __builtin_amdgcn_mfma_f32_16x16x32_bf16(af0, bvb[q], acc[0][6 + q], 0, 0, 0);
      acc[1][6 + q] = __builtin_amdgcn_mfma_f32_16x16x32_bf16(af1, bvb[q], acc[1][6 + q], 0, 0, 0);
    }
    #pragma unroll
    for (int q = 0; q < 6; ++q) {
      acc[0][12 + q] = __builtin_amdgcn_mfma_f32_16x16x32_bf16(af0, bva[q], acc[0][12 + q], 0, 0, 0);
      acc[1][12 + q] = __builtin_amdgcn_mfma_f32_16x16x32_bf16(af1, bva[q], acc[1][12 + q], 0, 0, 0);
    }
  }

  // epilogue: fp32 partials P[z][j][i]
  float* Pp = Pb + (size_t)blockIdx.z * PE;
  #pragma unroll
  for (int s = 0; s < 2; ++s) {
    const int i = i0w + s * 16 + ((lane >> 4) << 2);
    #pragma unroll
    for (int nf = 0; nf < 18; ++nf) {
      const int j = nf * 16 + l15;
      *(f32x4*)(Pp + (size_t)j * NSER + i) = acc[s][nf];
    }
  }
}

// ---------------- reduce NS fp32 partial slots -> bf16 mat ----------------
template <int NS>
__global__ __launch_bounds__(256) void k_reduce(const float* __restrict__ P,
                                                u16* __restrict__ o) {
  const size_t i = ((size_t)blockIdx.x * 256 + threadIdx.x) * 4;
  f32x4 s = *(const f32x4*)(P + i);
  #pragma unroll
  for (int k = 1; k < NS; ++k)
    s += *(const f32x4*)(P + (size_t)k * PE + i);
  u16x4 w;
  #pragma unroll
  for (int r = 0; r < 4; ++r) w[r] = f2bf(s[r]);
  *(u16x4*)(o + i) = w;
}

// z=0: P[0..3]->m2b, z=1: P[4..7]->m3b
__global__ __launch_bounds__(256) void k_reduce_pair(const float* __restrict__ P,
                                                     u16* __restrict__ m2b,
                                                     u16* __restrict__ m3b) {
  const float* p = P + (size_t)blockIdx.z * (4 * PE);
  u16* o = blockIdx.z ? m3b : m2b;
  const size_t i = ((size_t)blockIdx.x * 256 + threadIdx.x) * 4;
  f32x4 s = *(const f32x4*)(p + i);
  #pragma unroll
  for (int k = 1; k < 4; ++k)
    s += *(const f32x4*)(p + (size_t)k * PE + i);
  u16x4 w;
  #pragma unroll
  for (int r = 0; r < 4; ++r) w[r] = f2bf(s[r]);
  *(u16x4*)(o + i) = w;
}

// ---------------- final: out = X*W0' + m1*W1' + m2*W2' + m3*W3' + m4*W4' + bias ----
// BIG=1: m2 from bf16 m2b, m4 = sum P[0..7]. BIG=0: m2 = sum P[0..3], m4 = sum P[4..7].
template <int BIG>
__global__ __launch_bounds__(256) void k_final(const float* __restrict__ weight,
                                               const float* __restrict__ biases,
                                               const u16* __restrict__ Xb,
                                               const u16* __restrict__ m1b,
                                               const u16* __restrict__ m3b,
                                               const u16* __restrict__ m2b,
                                               const float* __restrict__ P,
                                               float* __restrict__ out) {
  __shared__ float w2[330][32];
  const int nt = blockIdx.x, b = blockIdx.y, oh = blockIdx.z;
  const int n0 = nt * 64;
  const int t = threadIdx.x;
  const int lane = t & 63, wv = t >> 6;
  {
    const int ol = t & 31;
    const int o = oh * 32 + ol;
    for (int f = t >> 5; f < 66; f += 8) {
      const float v0 = weight[(f * 5 + 0) * 64 + o];
      const float v1 = weight[(f * 5 + 1) * 64 + o];
      const float v2 = weight[(f * 5 + 2) * 64 + o];
      const float v3 = weight[(f * 5 + 3) * 64 + o];
      const float v4 = weight[(f * 5 + 4) * 64 + o];
      w2[f * 5 + 0][ol] = v0 - v2;   // X coefficient
      w2[f * 5 + 1][ol] = v1 - v4;   // m1
      w2[f * 5 + 2][ol] = 2.f * v2;  // m2
      w2[f * 5 + 3][ol] = v3;        // m3
      w2[f * 5 + 4][ol] = 2.f * v4;  // m4
    }
  }
  __syncthreads();
  const int ob = oh * 32 + wv * 8;
  float acc[8];
  #pragma unroll
  for (int i = 0; i < 8; ++i) acc[i] = biases[ob + i];
  for (int f = 0; f < 66; ++f) {
    const size_t base = (size_t)(f * 4 + b) * NSER + n0 + lane;
    float y[5];
    y[0] = bf2f(Xb[base]);
    y[1] = bf2f(m1b[base]);
    y[3] = bf2f(m3b[base]);
    if (BIG) {
      y[2] = bf2f(m2b[base]);
      float s = P[base];
      #pragma unroll
      for (int k = 1; k < 8; ++k) s += P[(size_t)k * PE + base];
      y[4] = s;
    } else {
      y[2] = P[base] + P[PE + base] + P[2 * PE + base] + P[3 * PE + base];
      y[4] = P[4 * PE + base] + P[5 * PE + base] + P[6 * PE + base] + P[7 * PE + base];
    }
    #pragma unroll
    for (int mat = 0; mat < 5; ++mat) {
      const float* wr = &w2[f * 5 + mat][wv * 8];
      #pragma unroll
      for (int i = 0; i < 8; ++i) acc[i] = fmaf(y[mat], wr[i], acc[i]);
    }
  }
  float* op = out + (size_t)b * (NSER * 64) + (size_t)(n0 + lane) * 64 + ob;
  #pragma unroll
  for (int i = 0; i < 8; ++i) op[i] = acc[i];
}

extern "C" void kernel_launch(void* const* d_in, const int* in_sizes, int n_in,
                              void* d_out, int out_size, void* d_ws, size_t ws_size,
                              hipStream_t stream) {
  const float* inputs = (const float*)d_in[0];
  const float* state  = (const float*)d_in[1];
  const float* s0     = (const float*)d_in[2];
  const float* s1     = (const float*)d_in[3];
  const float* weight = (const float*)d_in[4];
  const float* biases = (const float*)d_in[5];
  float* out = (float*)d_out;

  char* ws = (char*)d_ws;
  u16* Xb  = (u16*)ws;                           // 2,359,296 B
  u16* m1b = Xb + MATSZ;
  u16* m3b = m1b + MATSZ;
  const size_t SMALL_P_OFF = (size_t)3 * 2359296;        // 44,826,624 total (proven)
  const size_t BIG_P_OFF   = (size_t)4 * 2359296;        // 47,185,920 total
  const bool big = ws_size >= BIG_P_OFF + 8ull * 4718592;

  k_build_x<<<dim3(64, 4, 1), 256, 0, stream>>>(inputs, state, Xb);

  if (big) {
    u16* m2b = m3b + MATSZ;
    float* P = (float*)(ws + BIG_P_OFF);
    // m1 = S0 @ X, KC=8 -> P[0..7] (1024 waves)
    k_gemm<8><<<dim3(64, 1, 8), 128, 0, stream>>>(s0, s0, Xb, P);
    k_reduce<8><<<dim3(1152, 1, 1), 256, 0, stream>>>(P, m1b);
    // m2 = S0 @ m1 -> P[0..3]; m3 = S1 @ m1 -> P[4..7]
    k_gemm<4><<<dim3(64, 1, 8), 128, 0, stream>>>(s0, s1, m1b, P);
    k_reduce_pair<<<dim3(1152, 1, 2), 256, 0, stream>>>(P, m2b, m3b);
    // m4 = S1 @ m3, KC=8 -> P[0..7]
    k_gemm<8><<<dim3(64, 1, 8), 128, 0, stream>>>(s1, s1, m3b, P);
    k_final<1><<<dim3(64, 4, 2), 256, 0, stream>>>(weight, biases, Xb, m1b, m3b, m2b, P, out);
  } else {
    float* P = (float*)(ws + SMALL_P_OFF);
    // m1 = S0 @ X, KC=8 -> P[0..7]
    k_gemm<8><<<dim3(64, 1, 8), 128, 0, stream>>>(s0, s0, Xb, P);
    k_reduce<8><<<dim3(1152, 1, 1), 256, 0, stream>>>(P, m1b);
    // m2 -> P[0..3] (live till final); m3 -> P[4..7]
    k_gemm<4><<<dim3(64, 1, 8), 128, 0, stream>>>(s0, s1, m1b, P);
    k_reduce<4><<<dim3(1152, 1, 1), 256, 0, stream>>>(P + 4 * PE, m3b);
    // m4 = S1 @ m3, KC=4 -> P[4..7] (m2 partials preserved)
    k_gemm<4><<<dim3(64, 1, 4), 128, 0, stream>>>(s1, s1, m3b, P + 4 * PE);
    k_final<0><<<dim3(64, 4, 2), 256, 0, stream>>>(weight, biases, Xb, m1b, m3b, nullptr, P, out);
  }
}

// Round 8
// 156.577 us; speedup vs baseline: 1.5344x; 1.5344x over previous
//
#include <hip/hip_runtime.h>
#include <stdint.h>

typedef unsigned short u16;
typedef u16 u16x4 __attribute__((ext_vector_type(4)));
typedef u16 u16x8 __attribute__((ext_vector_type(8)));
typedef __bf16 bf16x8 __attribute__((ext_vector_type(8)));
typedef float f32x4 __attribute__((ext_vector_type(4)));

#define NSER 4096
#define KDIM 4096
#define NCOLS 288                 // 264 padded to 288 (divisible by BN=96)
#define MATSZ (NCOLS * NSER)      // elements per transposed bf16 mat buffer
#define PE ((size_t)NCOLS * NSER) // fp32 partial slot elements (1,179,648)

__device__ __forceinline__ u16 f2bf(float f) {
  uint32_t u = __builtin_bit_cast(uint32_t, f);
  u += 0x7FFFu + ((u >> 16) & 1u);   // RNE; inputs are never NaN
  return (u16)(u >> 16);
}
__device__ __forceinline__ float bf2f(u16 h) {
  return __builtin_bit_cast(float, (uint32_t)h << 16);
}

typedef const void __attribute__((address_space(1)))* gas1p;
typedef void __attribute__((address_space(3)))* las3p;

__device__ __forceinline__ void gload16(const void* g, void* l) {
  __builtin_amdgcn_global_load_lds((gas1p)g, (las3p)l, 16, 0, 0);
}

// ---------------- build X^T [288][4096] bf16 ----------------
// Xt[f*4+b][n] = xs[b,n,f];  f<2 -> inputs[b][n*2+f], f>=2 -> state[b][n*64+(f-2)]
__global__ __launch_bounds__(256) void k_build_x(const float* __restrict__ inputs,
                                                 const float* __restrict__ state,
                                                 u16* __restrict__ xb) {
  __shared__ float tile[64][65];
  const int nt = blockIdx.x, b = blockIdx.y;
  const int n0 = nt * 64;
  const int t = threadIdx.x;
  {
    const int i = t >> 2;
    const int c0 = (t & 3) * 16;
    const float* sp = state + ((int64_t)b * NSER + (n0 + i)) * 64 + c0;
    #pragma unroll
    for (int q = 0; q < 4; ++q) {
      float4 v = *(const float4*)(sp + q * 4);
      tile[i][c0 + q * 4 + 0] = v.x;
      tile[i][c0 + q * 4 + 1] = v.y;
      tile[i][c0 + q * 4 + 2] = v.z;
      tile[i][c0 + q * 4 + 3] = v.w;
    }
  }
  __syncthreads();
  const int wv = t >> 6, lane = t & 63;
  #pragma unroll
  for (int it = 0; it < 16; ++it) {
    const int d = wv + 4 * it;  // 0..63
    xb[(size_t)((2 + d) * 4 + b) * NSER + n0 + lane] = f2bf(tile[lane][d]);
  }
  if (t < 128) {
    const int c = t >> 6, j = t & 63;
    xb[(size_t)(c * 4 + b) * NSER + n0 + j] =
        f2bf(inputs[(int64_t)b * (NSER * 2) + (int64_t)(n0 + j) * 2 + c]);
  }
  if (b == 0) {  // zero pad rows 264..287
    for (int idx = t; idx < 24 * 64; idx += 256)
      xb[(size_t)(264 + idx / 64) * NSER + n0 + (idx & 63)] = 0;
  }
}

// ---------------- GEMM: P[z][j][i] = sum_k A[i][k] * B^T[j][k] ----------------
// Per-unit A staging mode: 0 = fp32 A (reg-staged -> bf16 ds_write, optional bf16
// write-back to global), 1 = bf16 A via global_load_lds (pre-swizzled source).
// B is always bf16 via global_load_lds. Double-buffered LDS, __syncthreads loop
// (round-4 proven structure). BM=64/BN=96/BK=64, 40KB LDS -> 4 blocks/CU.
#define BM 64
#define BN 96
#define BK 64
#define ABYTES (BM * BK * 2)      // 8192
#define BBYTES (BN * BK * 2)      // 12288
#define BUFSZ  (ABYTES + BBYTES)  // 20480

template <int KCC, int M0, int M1>
__global__ __launch_bounds__(256) void k_gemm(const float* __restrict__ Af0,
                                              const float* __restrict__ Af1,
                                              const u16* __restrict__ Ab0,
                                              const u16* __restrict__ Ab1,
                                              u16* __restrict__ wb0,
                                              u16* __restrict__ wb1,
                                              const u16* __restrict__ Bm,
                                              float* __restrict__ Pb) {
  int kc = blockIdx.z;
  int unit = 0;
  if (kc >= KCC) { unit = 1; kc -= KCC; }
  const int mode = unit ? M1 : M0;          // folds to const when M0==M1
  const float* Af = unit ? Af1 : Af0;
  const u16* Ab = unit ? Ab1 : Ab0;
  u16* wb = unit ? wb1 : wb0;
  const int i0 = blockIdx.x * BM;
  const int j0 = blockIdx.y * BN;
  const int t = threadIdx.x;
  const int wid = t >> 6, lane = t & 63;
  const int NKT = KDIM / KCC / BK;
  const int k0 = kc * (KDIM / KCC);
  const bool do_wb = (mode == 0) && (wb != nullptr) && (blockIdx.y == 0);

  __shared__ char smem[2 * BUFSZ];

  // A staging addresses. 2 slots x (8 rows x 8 lanes).
  int a_row[2], a_grow[2], a_ldst[2], a_srcb[2];
  #pragma unroll
  for (int s = 0; s < 2; ++s) {
    a_row[s] = (wid * 2 + s) * 8 + (lane >> 3);             // 0..63
    a_grow[s] = a_row[s] * KDIM + (lane & 7) * 8;           // fp32 elem offset
    a_ldst[s] = a_row[s] * 128 + 16 * ((lane & 7) ^ (a_row[s] & 7));  // LDS byte dest
    a_srcb[s] = a_row[s] * (KDIM * 2) + 16 * ((lane & 7) ^ (a_row[s] & 7)); // bf16 pre-swz src
  }
  // B staging: pre-swizzled global source, linear LDS dest. 3 slots x 8 rows.
  int b_src[3];
  #pragma unroll
  for (int s = 0; s < 3; ++s) {
    const int row = (wid * 3 + s) * 8 + (lane >> 3);        // 0..95
    b_src[s] = row * (KDIM * 2) + 16 * ((lane & 7) ^ (row & 7));
  }
  const float* Agf = Af ? Af + (int64_t)i0 * KDIM + k0 : nullptr;
  const char* Agb = Ab ? (const char*)Ab + ((int64_t)i0 * KDIM + k0) * 2 : nullptr;
  u16* wbp = do_wb ? wb + (size_t)i0 * KDIM + k0 : nullptr;
  const char* Bg = (const char*)Bm + ((int64_t)j0 * KDIM + k0) * 2;

  // fragment LDS read offsets (swizzled). Wave tile 32x48: 2 mf x 3 nf.
  int aoffs[2], axors[2];
  #pragma unroll
  for (int mf = 0; mf < 2; ++mf) {
    const int row = (wid >> 1) * 32 + mf * 16 + (lane & 15);
    aoffs[mf] = row * 128;
    axors[mf] = (row & 7) << 4;
  }
  int boffs[3], bxors[3];
  #pragma unroll
  for (int nf = 0; nf < 3; ++nf) {
    const int row = (wid & 1) * 48 + nf * 16 + (lane & 15);
    boffs[nf] = ABYTES + row * 128;
    bxors[nf] = (row & 7) << 4;
  }
  const int klane = (lane >> 4) * 16;

  f32x4 acc[2][3];
  #pragma unroll
  for (int mf = 0; mf < 2; ++mf)
    #pragma unroll
    for (int nf = 0; nf < 3; ++nf)
      acc[mf][nf] = (f32x4){0.f, 0.f, 0.f, 0.f};

  f32x4 areg[2][2];

  // ---- prologue: stage kt=0 into buf 0 ----
  #pragma unroll
  for (int s = 0; s < 3; ++s)
    gload16(Bg + b_src[s], smem + ABYTES + (wid * 3 + s) * 1024);
  if (mode == 1) {
    #pragma unroll
    for (int s = 0; s < 2; ++s)
      gload16(Agb + a_srcb[s], smem + (wid * 2 + s) * 1024);
  } else {
    #pragma unroll
    for (int s = 0; s < 2; ++s) {
      areg[s][0] = *(const f32x4*)(Agf + a_grow[s]);
      areg[s][1] = *(const f32x4*)(Agf + a_grow[s] + 4);
    }
    #pragma unroll
    for (int s = 0; s < 2; ++s) {
      u16x8 w;
      #pragma unroll
      for (int q = 0; q < 4; ++q) { w[q] = f2bf(areg[s][0][q]); w[4 + q] = f2bf(areg[s][1][q]); }
      *(u16x8*)(smem + a_ldst[s]) = w;
      if (do_wb) *(u16x8*)(wbp + a_grow[s]) = w;
    }
  }
  __syncthreads();

  for (int kt = 0; kt < NKT; ++kt) {
    const int cur = kt & 1;
    char* sbuf = smem + (cur ^ 1) * BUFSZ;
    if (kt + 1 < NKT) {
      if (mode == 0) {
        const float* Ak = Agf + (kt + 1) * BK;
        #pragma unroll
        for (int s = 0; s < 2; ++s) {         // A reg-loads first (oldest vmcnt)
          areg[s][0] = *(const f32x4*)(Ak + a_grow[s]);
          areg[s][1] = *(const f32x4*)(Ak + a_grow[s] + 4);
        }
      }
      const char* Bk = Bg + (kt + 1) * (BK * 2);
      #pragma unroll
      for (int s = 0; s < 3; ++s)
        gload16(Bk + b_src[s], sbuf + ABYTES + (wid * 3 + s) * 1024);
      if (mode == 1) {
        const char* Ak = Agb + (kt + 1) * (BK * 2);
        #pragma unroll
        for (int s = 0; s < 2; ++s)
          gload16(Ak + a_srcb[s], sbuf + (wid * 2 + s) * 1024);
      }
    }
    const char* sb = smem + cur * BUFSZ;
    #pragma unroll
    for (int kk = 0; kk < 2; ++kk) {
      const int kb = kk * 64 + klane;
      bf16x8 af[2], bfv[3];
      #pragma unroll
      for (int mf = 0; mf < 2; ++mf)
        af[mf] = *(const bf16x8*)(sb + aoffs[mf] + (kb ^ axors[mf]));
      #pragma unroll
      for (int nf = 0; nf < 3; ++nf)
        bfv[nf] = *(const bf16x8*)(sb + boffs[nf] + (kb ^ bxors[nf]));
      #pragma unroll
      for (int mf = 0; mf < 2; ++mf)
        #pragma unroll
        for (int nf = 0; nf < 3; ++nf)
          acc[mf][nf] = __builtin_amdgcn_mfma_f32_16x16x32_bf16(af[mf], bfv[nf],
                                                                acc[mf][nf], 0, 0, 0);
    }
    if (mode == 0 && kt + 1 < NKT) {  // write-late: A regs -> LDS (+ global bf16 write-back)
      #pragma unroll
      for (int s = 0; s < 2; ++s) {
        u16x8 w;
        #pragma unroll
        for (int q = 0; q < 4; ++q) { w[q] = f2bf(areg[s][0][q]); w[4 + q] = f2bf(areg[s][1][q]); }
        *(u16x8*)(sbuf + a_ldst[s]) = w;
        if (do_wb) *(u16x8*)(wbp + (kt + 1) * BK + a_grow[s]) = w;
      }
    }
    __syncthreads();
  }

  // epilogue: fp32 partials P[z][j][i]  (C/D frag: col(j)=lane&15, row(i)=(lane>>4)*4+r)
  float* Pp = Pb + (size_t)blockIdx.z * PE;
  #pragma unroll
  for (int mf = 0; mf < 2; ++mf) {
    const int i = i0 + (wid >> 1) * 32 + mf * 16 + ((lane >> 4) << 2);
    #pragma unroll
    for (int nf = 0; nf < 3; ++nf) {
      const int j = j0 + (wid & 1) * 48 + nf * 16 + (lane & 15);
      *(f32x4*)(Pp + (size_t)j * NSER + i) = acc[mf][nf];
    }
  }
}

// ---------------- reduce NS fp32 partial slots -> bf16 mat ----------------
template <int NS>
__global__ __launch_bounds__(256) void k_reduce(const float* __restrict__ P,
                                                u16* __restrict__ o) {
  const size_t i = ((size_t)blockIdx.x * 256 + threadIdx.x) * 4;
  f32x4 s = *(const f32x4*)(P + i);
  #pragma unroll
  for (int k = 1; k < NS; ++k)
    s += *(const f32x4*)(P + (size_t)k * PE + i);
  u16x4 w;
  #pragma unroll
  for (int r = 0; r < 4; ++r) w[r] = f2bf(s[r]);
  *(u16x4*)(o + i) = w;
}

// ---------------- final: out = X*W0' + m1*W1' + m2*W2' + m3*W3' + m4*W4' + bias ----
// m2 from 4 fp32 partials P[0..3], m4 from P[4..7].
__global__ __launch_bounds__(256) void k_final(const float* __restrict__ weight,
                                               const float* __restrict__ biases,
                                               const u16* __restrict__ Xb,
                                               const u16* __restrict__ m1b,
                                               const u16* __restrict__ m3b,
                                               const float* __restrict__ P,
                                               float* __restrict__ out) {
  __shared__ float w2[330][32];
  const int nt = blockIdx.x, b = blockIdx.y, oh = blockIdx.z;
  const int n0 = nt * 64;
  const int t = threadIdx.x;
  const int lane = t & 63, wv = t >> 6;
  {
    const int ol = t & 31;
    const int o = oh * 32 + ol;
    for (int f = t >> 5; f < 66; f += 8) {
      const float v0 = weight[(f * 5 + 0) * 64 + o];
      const float v1 = weight[(f * 5 + 1) * 64 + o];
      const float v2 = weight[(f * 5 + 2) * 64 + o];
      const float v3 = weight[(f * 5 + 3) * 64 + o];
      const float v4 = weight[(f * 5 + 4) * 64 + o];
      w2[f * 5 + 0][ol] = v0 - v2;   // X coefficient
      w2[f * 5 + 1][ol] = v1 - v4;   // m1
      w2[f * 5 + 2][ol] = 2.f * v2;  // m2
      w2[f * 5 + 3][ol] = v3;        // m3
      w2[f * 5 + 4][ol] = 2.f * v4;  // m4
    }
  }
  __syncthreads();
  const int ob = oh * 32 + wv * 8;
  float acc[8];
  #pragma unroll
  for (int i = 0; i < 8; ++i) acc[i] = biases[ob + i];
  for (int f = 0; f < 66; ++f) {
    const size_t base = (size_t)(f * 4 + b) * NSER + n0 + lane;
    float y[5];
    y[0] = bf2f(Xb[base]);
    y[1] = bf2f(m1b[base]);
    y[2] = P[base] + P[PE + base] + P[2 * PE + base] + P[3 * PE + base];
    y[3] = bf2f(m3b[base]);
    y[4] = P[4 * PE + base] + P[5 * PE + base] + P[6 * PE + base] + P[7 * PE + base];
    #pragma unroll
    for (int mat = 0; mat < 5; ++mat) {
      const float* wr = &w2[f * 5 + mat][wv * 8];
      #pragma unroll
      for (int i = 0; i < 8; ++i) acc[i] = fmaf(y[mat], wr[i], acc[i]);
    }
  }
  float* op = out + (size_t)b * (NSER * 64) + (size_t)(n0 + lane) * 64 + ob;
  #pragma unroll
  for (int i = 0; i < 8; ++i) op[i] = acc[i];
}

extern "C" void kernel_launch(void* const* d_in, const int* in_sizes, int n_in,
                              void* d_out, int out_size, void* d_ws, size_t ws_size,
                              hipStream_t stream) {
  const float* inputs = (const float*)d_in[0];
  const float* state  = (const float*)d_in[1];
  const float* s0     = (const float*)d_in[2];
  const float* s1     = (const float*)d_in[3];
  const float* weight = (const float*)d_in[4];
  const float* biases = (const float*)d_in[5];
  float* out = (float*)d_out;

  char* ws = (char*)d_ws;
  u16* Xb  = (u16*)ws;                          // 2,359,296 B
  u16* m1b = Xb + MATSZ;
  u16* m3b = m1b + MATSZ;                       // ends at 7,077,888

  const size_t SB = 33554432;                   // one bf16 S matrix
  const size_t PB = 8ull * 4718592;             // 8 fp32 partial slots
  const size_t NEED_BIG = 7077888 + 2 * SB + PB;   // 111,935,488
  const size_t NEED_MID = 7077888 + SB + PB;       //  78,381,056

  k_build_x<<<dim3(64, 4, 1), 256, 0, stream>>>(inputs, state, Xb);

  if (ws_size >= NEED_BIG) {
    u16* S0b = (u16*)(ws + 7077888);
    u16* S1b = S0b + (SB / 2);
    float* P = (float*)(ws + 7077888 + 2 * SB);
    // m1 = S0 @ X (fp32 A + write-back S0b), KC=8 -> P[0..7]
    k_gemm<8, 0, 0><<<dim3(64, 3, 8), 256, 0, stream>>>(s0, s0, nullptr, nullptr,
                                                        S0b, S0b, Xb, P);
    k_reduce<8><<<dim3(1152, 1, 1), 256, 0, stream>>>(P, m1b);
    // m2 = S0b(bf16) @ m1 -> P[0..3]; m3 = S1(fp32, write-back S1b) @ m1 -> P[4..7]
    k_gemm<4, 1, 0><<<dim3(64, 3, 8), 256, 0, stream>>>(nullptr, s1, S0b, nullptr,
                                                        nullptr, S1b, m1b, P);
    k_reduce<4><<<dim3(1152, 1, 1), 256, 0, stream>>>(P + 4 * PE, m3b);
    // m4 = S1b(bf16) @ m3 -> P[4..7]
    k_gemm<4, 1, 1><<<dim3(64, 3, 4), 256, 0, stream>>>(nullptr, nullptr, S1b, S1b,
                                                        nullptr, nullptr, m3b, P + 4 * PE);
    k_final<<<dim3(64, 4, 2), 256, 0, stream>>>(weight, biases, Xb, m1b, m3b, P, out);
  } else if (ws_size >= NEED_MID) {
    u16* S1b = (u16*)(ws + 7077888);
    float* P = (float*)(ws + 7077888 + SB);
    k_gemm<8, 0, 0><<<dim3(64, 3, 8), 256, 0, stream>>>(s0, s0, nullptr, nullptr,
                                                        nullptr, nullptr, Xb, P);
    k_reduce<8><<<dim3(1152, 1, 1), 256, 0, stream>>>(P, m1b);
    // m2 = S0(fp32) @ m1; m3 = S1(fp32, write-back S1b) @ m1
    k_gemm<4, 0, 0><<<dim3(64, 3, 8), 256, 0, stream>>>(s0, s1, nullptr, nullptr,
                                                        nullptr, S1b, m1b, P);
    k_reduce<4><<<dim3(1152, 1, 1), 256, 0, stream>>>(P + 4 * PE, m3b);
    k_gemm<4, 1, 1><<<dim3(64, 3, 4), 256, 0, stream>>>(nullptr, nullptr, S1b, S1b,
                                                        nullptr, nullptr, m3b, P + 4 * PE);
    k_final<<<dim3(64, 4, 2), 256, 0, stream>>>(weight, biases, Xb, m1b, m3b, P, out);
  } else {
    // round-4 proven fallback: all fp32 A, 44.8 MB
    float* P = (float*)(ws + 7077888);
    k_gemm<8, 0, 0><<<dim3(64, 3, 8), 256, 0, stream>>>(s0, s0, nullptr, nullptr,
                                                        nullptr, nullptr, Xb, P);
    k_reduce<8><<<dim3(1152, 1, 1), 256, 0, stream>>>(P, m1b);
    k_gemm<4, 0, 0><<<dim3(64, 3, 8), 256, 0, stream>>>(s0, s1, nullptr, nullptr,
                                                        nullptr, nullptr, m1b, P);
    k_reduce<4><<<dim3(1152, 1, 1), 256, 0, stream>>>(P + 4 * PE, m3b);
    k_gemm<4, 0, 0><<<dim3(64, 3, 4), 256, 0, stream>>>(s1, s1, nullptr, nullptr,
                                                        nullptr, nullptr, m3b, P + 4 * PE);
    k_final<<<dim3(64, 4, 2), 256, 0, stream>>>(weight, biases, Xb, m1b, m3b, P, out);
  }
}